// Round 1
// baseline (636.267 us; speedup 1.0000x reference)
//
#include <hip/hip_runtime.h>

// ---------- problem constants ----------
#define HW_   576
#define BHW   1152      // B*HW
#define DD    2048
#define CLIPC 1024
#define NSEQ  768
#define LL    25

typedef __bf16 bf16x8 __attribute__((ext_vector_type(8)));
typedef float  f32x4  __attribute__((ext_vector_type(4)));
typedef unsigned short u16;

__device__ __forceinline__ float bf2f(u16 u){
  union { unsigned int i; float f; } v; v.i = ((unsigned int)u) << 16; return v.f;
}
__device__ __forceinline__ u16 f2bf(float f){
  union { float f; unsigned int i; } v; v.f = f;
  unsigned int u = v.i;
  return (u16)((u + 0x7fffu + ((u >> 16) & 1u)) >> 16);  // RNE
}

// async global->LDS, 16B per lane; LDS dest = wave-uniform base + lane*16
__device__ __forceinline__ void gld_lds16(const void* g, void* l){
  __builtin_amdgcn_global_load_lds((__attribute__((address_space(1))) void*)g,
                                   (__attribute__((address_space(3))) void*)l,
                                   16, 0, 0);
}

// ---------- setup: image-token index per sample + zero the cos accumulator ----------
__global__ void setup_k(const int* __restrict__ ids, int* __restrict__ idxbuf,
                        float* __restrict__ acc){
  const int lane = threadIdx.x;
  for (int b = 0; b < 2; b++){
    int best = 0x7fffffff;
    for (int i = lane; i < NSEQ; i += 64)
      if (ids[b*NSEQ + i] == -200 && i < best) best = i;
    for (int off = 32; off; off >>= 1){ int o = __shfl_xor(best, off); best = min(best, o); }
    if (lane == 0) idxbuf[b] = best;
  }
  if (lane == 0) acc[0] = 0.f;
}

// ---------- fp32 -> bf16 weight conversion (norm_w || input_w -> B_all; output_w -> outw) ----------
__global__ void conv_weights(const float* __restrict__ norm_w, const float* __restrict__ input_w,
                             const float* __restrict__ output_w, u16* __restrict__ B_all,
                             u16* __restrict__ outw){
  const long n1 = 7L*CLIPC*DD, n2 = (long)CLIPC*DD, n3 = (long)CLIPC*CLIPC;
  long idx = ((long)blockIdx.x*256 + threadIdx.x) * 4;
  if (idx >= n1 + n2 + n3) return;
  const float* s; u16* d;
  if (idx < n1)         { s = norm_w  + idx;            d = B_all + idx; }
  else if (idx < n1+n2) { s = input_w + (idx - n1);     d = B_all + idx; }
  else                  { s = output_w + (idx - n1 - n2); d = outw + (idx - n1 - n2); }
  float4 v = *(const float4*)s;
  union { u16 u[4]; unsigned long long q; } pk;
  pk.u[0] = f2bf(v.x); pk.u[1] = f2bf(v.y); pk.u[2] = f2bf(v.z); pk.u[3] = f2bf(v.w);
  *(unsigned long long*)d = pk.q;
}

// ---------- clip_w (1024 x 588) -> bf16 padded to K=608 ----------
__global__ void conv_clipw(const float* __restrict__ clip_w, u16* __restrict__ dst){
  const int c = blockIdx.x, tid = threadIdx.x;
  for (int k = tid; k < 608; k += 128)
    dst[c*608 + k] = (k < 588) ? f2bf(clip_w[c*588 + k]) : (u16)0;
}

// ---------- patchify images -> bf16 [1152][608] (K padded) ----------
__global__ void conv_patches(const float* __restrict__ images, u16* __restrict__ dst){
  const int r = blockIdx.x, tid = threadIdx.x;
  const int b = r / HW_, n = r % HW_;
  const int hi = n / 24, wi = n % 24;
  for (int p = tid; p < 608; p += 128){
    float v = 0.f;
    if (p < 588){
      int c3 = p / 196, rem = p - c3*196;
      int ph = rem / 14, pw = rem - ph*14;
      v = images[(((long)b*4 + c3)*336 + hi*14 + ph)*336 + wi*14 + pw];
    }
    dst[(long)r*608 + p] = f2bf(v);
  }
}

// ---------- gather token slice + LayerNorm -> A_all bf16 (slots 0..6 LN'd layers, slot 7 raw layer 24) ----------
__global__ void gather_ln(const float* __restrict__ feats, const int* __restrict__ idxbuf,
                          const float* __restrict__ gamma, const float* __restrict__ beta,
                          u16* __restrict__ A_all){
  const int r = blockIdx.x, g = blockIdx.y;
  const int b = r / HW_, n = r % HW_;
  const int hi = n / 24, wi = n % 24;
  const int tok = idxbuf[b] + 1 + hi*25 + wi;
  const int layer = (g < 7) ? (24 - g*4) : 24;
  const float* src = feats + (((long)(b*NSEQ + tok))*LL + layer)*DD;
  const int tid = threadIdx.x;
  float v[8];
#pragma unroll
  for (int k = 0; k < 8; k++) v[k] = src[tid + k*256];
  u16* dst = A_all + ((long)g*BHW + r)*DD;
  if (g == 7){
#pragma unroll
    for (int k = 0; k < 8; k++) dst[tid + k*256] = f2bf(v[k]);
    return;
  }
  float s = 0.f, q = 0.f;
#pragma unroll
  for (int k = 0; k < 8; k++){ s += v[k]; q += v[k]*v[k]; }
  for (int off = 32; off; off >>= 1){ s += __shfl_xor(s, off); q += __shfl_xor(q, off); }
  __shared__ float rs[4], rq[4];
  const int wave = tid >> 6, lane = tid & 63;
  if (lane == 0){ rs[wave] = s; rq[wave] = q; }
  __syncthreads();
  const float ts = rs[0]+rs[1]+rs[2]+rs[3];
  const float tq = rq[0]+rq[1]+rq[2]+rq[3];
  const float mu   = ts * (1.f/2048.f);
  const float var  = tq * (1.f/2048.f) - mu*mu;
  const float rstd = rsqrtf(var + 1e-5f);
  const float* gm = gamma + g*DD;
  const float* bt = beta  + g*DD;
#pragma unroll
  for (int k = 0; k < 8; k++){
    int d = tid + k*256;
    dst[d] = f2bf((v[k]-mu)*rstd*gm[d] + bt[d]);
  }
}

// ---------- MFMA GEMM: C[z] = A[z] (MxK, row-major) * B[z]^T (B is NxK row-major) ----------
// 128x128 tile, BK=32, 4 waves (each 64x64 via 4x4 of 16x16x32 MFMA), m97-style 2-barrier K-loop.
template<bool OUT_BF16>
__global__ __launch_bounds__(256, 2)
void gemm_bt(const u16* __restrict__ A, const u16* __restrict__ B,
             void* __restrict__ Cv, const float* __restrict__ bias, int bias_z,
             const u16* __restrict__ addsrc,
             int N, int K, long aSlot, long bSlot, long cSlot){
  const int z = blockIdx.z;
  const u16* Az = A + (long)z * aSlot;
  const u16* Bz = B + (long)z * bSlot;
  const int bm = blockIdx.x * 128;
  const int bn = blockIdx.y * 128;
  __shared__ alignas(16) u16 As[128*32];
  __shared__ alignas(16) u16 Bs[128*32];
  const int tid  = threadIdx.x;
  const int wave = tid >> 6, lane = tid & 63;
  const int wr = (wave >> 1) * 64, wc = (wave & 1) * 64;
  const int l15 = lane & 15, quad = lane >> 4;

  f32x4 acc[4][4] = {};

  // staging addressing: wave w stages rows [w*32, w*32+32) of both tiles, 2 insts x 16 rows
  const int  sRow = wave*32 + (lane >> 2);
  const int  sK   = (lane & 3) * 8;
  const u16* gA = Az + (long)(bm + sRow)*K + sK;
  const u16* gB = Bz + (long)(bn + sRow)*K + sK;
  const long r16 = (long)16 * K;
  u16* lA0 = &As[wave*1024]; u16* lA1 = lA0 + 512;
  u16* lB0 = &Bs[wave*1024]; u16* lB1 = lB0 + 512;

  for (int k0 = 0; k0 < K; k0 += 32){
    gld_lds16(gA + k0,        lA0);
    gld_lds16(gA + r16 + k0,  lA1);
    gld_lds16(gB + k0,        lB0);
    gld_lds16(gB + r16 + k0,  lB1);
    __syncthreads();                       // drains vmcnt then barrier
    bf16x8 af[4], bg[4];
#pragma unroll
    for (int i = 0; i < 4; i++) af[i] = *(const bf16x8*)&As[(wr + i*16 + l15)*32 + quad*8];
#pragma unroll
    for (int j = 0; j < 4; j++) bg[j] = *(const bf16x8*)&Bs[(wc + j*16 + l15)*32 + quad*8];
#pragma unroll
    for (int i = 0; i < 4; i++)
#pragma unroll
      for (int j = 0; j < 4; j++)
        acc[i][j] = __builtin_amdgcn_mfma_f32_16x16x32_bf16(af[i], bg[j], acc[i][j], 0, 0, 0);
    __syncthreads();                       // all waves done reading before next stage
  }

  const bool do_bias = (bias != nullptr) && (z == bias_z);
  const long cz = (long)z * cSlot;
#pragma unroll
  for (int i = 0; i < 4; i++)
#pragma unroll
    for (int j = 0; j < 4; j++)
#pragma unroll
      for (int rr = 0; rr < 4; rr++){
        const int row = bm + wr + i*16 + quad*4 + rr;   // C/D: row = quad*4+reg
        const int col = bn + wc + j*16 + l15;           //      col = lane&15
        float v = acc[i][j][rr];
        if (do_bias) v += bias[col];
        if (addsrc)  v += bf2f(addsrc[cz + (long)row*N + col]);
        if constexpr (OUT_BF16) ((u16*)Cv)[cz + (long)row*N + col] = f2bf(v);
        else                    ((float*)Cv)[cz + (long)row*N + col] = v;
      }
}

// ---------- attention: per (token,row r, head h) one wave; 6 kv slots ----------
__global__ void attn_k(const u16* __restrict__ C_all, u16* __restrict__ fuse){
  const int r = blockIdx.x, h = blockIdx.y, lane = threadIdx.x;
  const long slot = (long)BHW * CLIPC;
  const long rb = (long)r * CLIPC;
  const int c0 = h*128 + lane, c1 = c0 + 64;
  const float q0 = bf2f(C_all[rb + c0]), q1 = bf2f(C_all[rb + c1]);
  float k0v[6], k1v[6], dt[6];
#pragma unroll
  for (int t = 0; t < 6; t++){
    const u16* base = C_all + (long)(t+1)*slot + rb;
    k0v[t] = bf2f(base[c0]); k1v[t] = bf2f(base[c1]);
    dt[t] = q0*k0v[t] + q1*k1v[t];
  }
#pragma unroll
  for (int t = 0; t < 6; t++)
    for (int off = 32; off; off >>= 1) dt[t] += __shfl_xor(dt[t], off);
  float l[6], e[6];
#pragma unroll
  for (int t = 0; t < 6; t++) l[t] = dt[t] * 0.03125f;   // SCALE = 1024^-0.5
  float m = l[0];
#pragma unroll
  for (int t = 1; t < 6; t++) m = fmaxf(m, l[t]);
  float ssum = 0.f;
#pragma unroll
  for (int t = 0; t < 6; t++){ e[t] = __expf(l[t] - m); ssum += e[t]; }
  const float inv = 1.f / ssum;
  float f0 = 0.f, f1 = 0.f;
#pragma unroll
  for (int t = 0; t < 6; t++){ const float a = e[t]*inv; f0 += a*k0v[t]; f1 += a*k1v[t]; }
  fuse[rb + c0] = f2bf(f0);
  fuse[rb + c1] = f2bf(f1);
}

// ---------- cosine per row, accumulate sum of cos ----------
__global__ void cos_k(const float* __restrict__ outb, const float* __restrict__ cf,
                      float* __restrict__ acc){
  const int r = blockIdx.x, tid = threadIdx.x;
  const long rb = (long)r * CLIPC;
  float soc = 0.f, soo = 0.f, scc = 0.f;
#pragma unroll
  for (int k = 0; k < 4; k++){
    const int i = tid + k*256;
    const float o = outb[rb + i], c = cf[rb + i];
    soc += o*c; soo += o*o; scc += c*c;
  }
  for (int off = 32; off; off >>= 1){
    soc += __shfl_xor(soc, off); soo += __shfl_xor(soo, off); scc += __shfl_xor(scc, off);
  }
  __shared__ float r0[4], r1[4], r2[4];
  const int wave = tid >> 6, lane = tid & 63;
  if (lane == 0){ r0[wave] = soc; r1[wave] = soo; r2[wave] = scc; }
  __syncthreads();
  if (tid == 0){
    const float a = r0[0]+r0[1]+r0[2]+r0[3];
    const float b = r1[0]+r1[1]+r1[2]+r1[3];
    const float c = r2[0]+r2[1]+r2[2]+r2[3];
    atomicAdd(acc, a / fmaxf(sqrtf(b*c), 1e-8f));
  }
}

__global__ void fin_k(const float* __restrict__ acc, float* __restrict__ out){
  out[0] = 1.f - acc[0] * (1.f/1152.f);
}

extern "C" void kernel_launch(void* const* d_in, const int* in_sizes, int n_in,
                              void* d_out, int out_size, void* d_ws, size_t ws_size,
                              hipStream_t stream){
  const int*   input_ids = (const int*)  d_in[0];
  const float* images    = (const float*)d_in[1];
  const float* all_feats = (const float*)d_in[2];
  // d_in[3] = patch_hw (unused; always 24)
  const float* norm_gamma = (const float*)d_in[4];
  const float* norm_beta  = (const float*)d_in[5];
  const float* norm_w     = (const float*)d_in[6];
  const float* input_w    = (const float*)d_in[7];
  const float* input_b    = (const float*)d_in[8];
  const float* output_w   = (const float*)d_in[9];
  const float* output_b   = (const float*)d_in[10];
  const float* clip_w     = (const float*)d_in[11];
  const float* clip_b     = (const float*)d_in[12];
  float* out = (float*)d_out;

  // ---- workspace layout (~107 MB) ----
  char* w = (char*)d_ws;
  int*   idxbuf = (int*)w;
  float* acc    = (float*)(w + 64);
  size_t off = 256;
  u16* A_all = (u16*)(w + off); off += 8L*BHW*DD*2;      // 37,748,736
  u16* B_all = (u16*)(w + off); off += 8L*CLIPC*DD*2;    // 33,554,432
  u16* C_all = (u16*)(w + off); off += 8L*BHW*CLIPC*2;   // 18,874,368
  u16* outw  = (u16*)(w + off); off += (long)CLIPC*CLIPC*2;
  u16* clipw = (u16*)(w + off); off += (long)CLIPC*608*2;
  u16* patch = (u16*)(w + off); off += (long)BHW*608*2;
  u16* fuse  = (u16*)(w + off); off += (long)BHW*CLIPC*2;
  float* cf   = (float*)(w + off); off += (long)BHW*CLIPC*4;
  float* outb = (float*)(w + off); off += (long)BHW*CLIPC*4;

  setup_k<<<1, 64, 0, stream>>>(input_ids, idxbuf, acc);
  conv_weights<<<17408, 256, 0, stream>>>(norm_w, input_w, output_w, B_all, outw);
  conv_clipw<<<1024, 128, 0, stream>>>(clip_w, clipw);
  conv_patches<<<1152, 128, 0, stream>>>(images, patch);
  gather_ln<<<dim3(1152, 8), 256, 0, stream>>>(all_feats, idxbuf, norm_gamma, norm_beta, A_all);

  // clip_feats = patches @ clip_w^T + clip_b  (fp32 out)
  gemm_bt<false><<<dim3(9, 8, 1), 256, 0, stream>>>(
      patch, clipw, cf, clip_b, 0, nullptr, CLIPC, 608, 0, 0, 0);

  // batched: slots 0..6 -> vis_j = xn_j @ norm_w[j]^T ; slot 7 -> inp = f24 @ input_w^T + input_b (bf16 out)
  gemm_bt<true><<<dim3(9, 8, 8), 256, 0, stream>>>(
      A_all, B_all, C_all, input_b, 7, nullptr, CLIPC, DD,
      (long)BHW*DD, (long)CLIPC*DD, (long)BHW*CLIPC);

  attn_k<<<dim3(1152, 8), 64, 0, stream>>>(C_all, fuse);

  // out = inp + fuse @ output_w^T + output_b (fp32 out; add = C_all slot 7)
  gemm_bt<false><<<dim3(9, 8, 1), 256, 0, stream>>>(
      fuse, outw, outb, output_b, 0, C_all + 7L*BHW*CLIPC, CLIPC, CLIPC, 0, 0, 0);

  cos_k<<<1152, 256, 0, stream>>>(outb, cf, acc);
  fin_k<<<1, 1, 0, stream>>>(acc, out);
}